// Round 1
// baseline (208.210 us; speedup 1.0000x reference)
//
#include <hip/hip_runtime.h>

// Problem constants: A=1, B=8, M=256, H=2048, E=8, K=2, N=2048
#define Bn 8
#define Mn 256
#define Hn 2048
#define En 8
#define Kn 2
#define Nn 2048

// d_ws layout: hs[Bn*Hn] floats, then wsum[En*Hn] floats (128 KB total)

// Fused reduction:
//  blocks [0, 4096):  one wave per (e,k) row of gate_up_proj -> wsum[e*H+k]
//  blocks [4096, 4608): hidden column reduction over m-chunks -> atomicAdd hs[b*H+k]
__global__ void reduce_kernel(const float* __restrict__ hidden,
                              const float* __restrict__ gup,
                              float* __restrict__ hs,
                              float* __restrict__ wsum) {
    const int bid = blockIdx.x;
    const int t   = threadIdx.x;
    if (bid < 4096) {
        // gate_up_proj row sums: row = e*H + k in [0, 16384); 4 waves/block
        const int wave = t >> 6;
        const int lane = t & 63;
        const int row  = bid * 4 + wave;
        const float4* p = (const float4*)(gup + (size_t)row * Nn);
        float acc = 0.f;
#pragma unroll
        for (int i = 0; i < 8; ++i) {
            float4 v = p[i * 64 + lane];   // 64 lanes x 16B = 1KB per step
            acc += (v.x + v.y) + (v.z + v.w);
        }
#pragma unroll
        for (int off = 32; off > 0; off >>= 1)
            acc += __shfl_down(acc, off, 64);
        if (lane == 0) wsum[row] = acc;
    } else {
        // hidden: hs[b,k] = sum_m hidden[b,m,k]; 512 blocks = 8 b x 8 ktile x 8 mchunk
        const int bi = bid - 4096;
        const int mc = bi & 7;          // m-chunk of 32
        const int kt = (bi >> 3) & 7;   // k-tile of 256
        const int b  = bi >> 6;
        const int k  = kt * 256 + t;
        const float* p = hidden + (size_t)b * Mn * Hn + (size_t)(mc * 32) * Hn + k;
        float acc = 0.f;
#pragma unroll
        for (int m = 0; m < 32; ++m)
            acc += p[(size_t)m * Hn];   // coalesced across threads each iter
        atomicAdd(&hs[b * Hn + k], acc);
    }
}

// out = sum_{b,e,k} sp[b,e] * hs[b,k] * wsum[e,k]   (single block)
__global__ void final_kernel(const float* __restrict__ sparsity,
                             const float* __restrict__ hs,
                             const float* __restrict__ wsum,
                             float* __restrict__ out) {
    __shared__ float sp[Bn][En];
    __shared__ float red[4];
    const int t = threadIdx.x;
    if (t < Bn * En) {
        const int b = t >> 3, e = t & 7;
        sp[b][e] = sparsity[b * (Kn * En) + e];   // sparsity[0, b, 0, e]
    }
    __syncthreads();
    float acc = 0.f;
    for (int k = t; k < Hn; k += 256) {
        float h[Bn];
#pragma unroll
        for (int b = 0; b < Bn; ++b) h[b] = hs[b * Hn + k];
#pragma unroll
        for (int e = 0; e < En; ++e) {
            float g = 0.f;
#pragma unroll
            for (int b = 0; b < Bn; ++b) g += sp[b][e] * h[b];
            acc += wsum[e * Hn + k] * g;
        }
    }
#pragma unroll
    for (int off = 32; off > 0; off >>= 1)
        acc += __shfl_down(acc, off, 64);
    const int lane = t & 63, wave = t >> 6;
    if (lane == 0) red[wave] = acc;
    __syncthreads();
    if (t == 0) out[0] = red[0] + red[1] + red[2] + red[3];
}

extern "C" void kernel_launch(void* const* d_in, const int* in_sizes, int n_in,
                              void* d_out, int out_size, void* d_ws, size_t ws_size,
                              hipStream_t stream) {
    const float* hidden   = (const float*)d_in[0];  // (1,8,256,2048) fp32
    const float* sparsity = (const float*)d_in[1];  // (1,8,2,8) fp32
    const float* gup      = (const float*)d_in[2];  // (1,8,2048,2048) fp32

    float* hs   = (float*)d_ws;          // Bn*Hn floats
    float* wsum = hs + Bn * Hn;          // En*Hn floats

    hipMemsetAsync(d_ws, 0, Bn * Hn * sizeof(float), stream);
    reduce_kernel<<<4096 + 512, 256, 0, stream>>>(hidden, gup, hs, wsum);
    final_kernel<<<1, 256, 0, stream>>>(sparsity, hs, wsum, (float*)d_out);
}